// Round 1
// baseline (784.049 us; speedup 1.0000x reference)
//
#include <hip/hip_runtime.h>
#include <hip/hip_bf16.h>

#define HDIM 64
#define INDIM 128
#define OUTDIM 32
#define SCAN_CHUNK 1024

// ---------------- degree count ----------------
__global__ void deg_kernel(const int* __restrict__ dst, int* __restrict__ deg, int e) {
    int i = blockIdx.x * blockDim.x + threadIdx.x;
    if (i < e) atomicAdd(&deg[dst[i]], 1);
}

// ---------------- 3-kernel exclusive scan of deg -> offs ----------------
__global__ void scan_blocks(const int* __restrict__ deg, int* __restrict__ offs,
                            int* __restrict__ bsums, int n) {
    __shared__ int sdata[256];
    int b = blockIdx.x, t = threadIdx.x;
    int base = b * SCAN_CHUNK + t * 4;
    int v[4];
    int s = 0;
    #pragma unroll
    for (int i = 0; i < 4; i++) {
        int idx = base + i;
        v[i] = (idx < n) ? deg[idx] : 0;
        s += v[i];
    }
    sdata[t] = s;
    __syncthreads();
    for (int off = 1; off < 256; off <<= 1) {
        int x = (t >= off) ? sdata[t - off] : 0;
        __syncthreads();
        sdata[t] += x;
        __syncthreads();
    }
    int run = sdata[t] - s;  // exclusive prefix of this thread within block
    #pragma unroll
    for (int i = 0; i < 4; i++) {
        int idx = base + i;
        if (idx < n) offs[idx] = run;
        run += v[i];
    }
    if (t == 255) bsums[b] = sdata[255];
}

__global__ void scan_bsums(int* __restrict__ bsums, int nb) {
    if (blockIdx.x == 0 && threadIdx.x == 0) {
        int run = 0;
        for (int b = 0; b < nb; b++) { int t = bsums[b]; bsums[b] = run; run += t; }
    }
}

__global__ void scan_add(int* __restrict__ offs, const int* __restrict__ bsums,
                         int n, int total) {
    int i = blockIdx.x * blockDim.x + threadIdx.x;
    if (i < n) offs[i] += bsums[i >> 10];
    if (i == 0) offs[n] = total;
}

// ---------------- CSR fill (src index + edge weight) ----------------
__global__ void fill_csr(const int* __restrict__ dst, const int* __restrict__ src,
                         const int* __restrict__ deg, const int* __restrict__ offs,
                         int* __restrict__ cursor, int* __restrict__ csr_src,
                         float* __restrict__ csr_w, int e) {
    int i = blockIdx.x * blockDim.x + threadIdx.x;
    if (i >= e) return;
    int d = dst[i], s = src[i];
    int pos = offs[d] + atomicAdd(&cursor[d], 1);
    csr_src[pos] = s;
    float nd = (float)deg[d] + 1.0f;
    float ns = (float)deg[s] + 1.0f;
    csr_w[pos] = rsqrtf(nd * ns);
}

// ---------------- h = x @ W_in  (128 -> 64) ----------------
__global__ void gemm_in(const float* __restrict__ x, const float* __restrict__ Win,
                        float* __restrict__ h, int n) {
    __shared__ float w[INDIM * HDIM];  // 32 KiB
    for (int i = threadIdx.x; i < INDIM * HDIM; i += blockDim.x) w[i] = Win[i];
    __syncthreads();
    int wave = threadIdx.x >> 6;
    int f = threadIdx.x & 63;
    int wpb = blockDim.x >> 6;
    for (int node = blockIdx.x * wpb + wave; node < n; node += gridDim.x * wpb) {
        const float* xr = x + (size_t)node * INDIM;
        float acc = 0.f;
        #pragma unroll 8
        for (int k = 0; k < INDIM; k++) acc += xr[k] * w[k * HDIM + f];
        h[(size_t)node * HDIM + f] = acc;
    }
}

// ---------------- agg[d] = sum_{e: dst=d} h[src]/norm ----------------
__global__ void aggregate(const float* __restrict__ h, const int* __restrict__ offs,
                          const int* __restrict__ csr_src, const float* __restrict__ csr_w,
                          float* __restrict__ agg, int n) {
    int wave = threadIdx.x >> 6;
    int f = threadIdx.x & 63;
    int node = blockIdx.x * (blockDim.x >> 6) + wave;
    if (node >= n) return;
    int j0 = offs[node], j1 = offs[node + 1];
    float acc = 0.f;
    for (int j = j0; j < j1; j++) {
        int s = csr_src[j];
        float wgt = csr_w[j];
        acc += h[(size_t)s * HDIM + f] * wgt;
    }
    agg[(size_t)node * HDIM + f] = acc;
}

// ---------------- h = relu((agg + h) @ W)  (64 -> 64, in-place) ----------------
__global__ void gemm_layer(const float* __restrict__ agg, float* __restrict__ h,
                           const float* __restrict__ W, int n) {
    __shared__ float w[HDIM * HDIM];  // 16 KiB
    for (int i = threadIdx.x; i < HDIM * HDIM; i += blockDim.x) w[i] = W[i];
    __syncthreads();
    int wave = threadIdx.x >> 6;
    int f = threadIdx.x & 63;
    int wpb = blockDim.x >> 6;
    for (int node = blockIdx.x * wpb + wave; node < n; node += gridDim.x * wpb) {
        float v = agg[(size_t)node * HDIM + f] + h[(size_t)node * HDIM + f];
        float acc = 0.f;
        #pragma unroll 8
        for (int k = 0; k < HDIM; k++) acc += __shfl(v, k) * w[k * HDIM + f];
        h[(size_t)node * HDIM + f] = fmaxf(acc, 0.f);
    }
}

// ---------------- out = h @ W_out  (64 -> 32) ----------------
__global__ void gemm_out(const float* __restrict__ h, const float* __restrict__ Wout,
                         float* __restrict__ out, int n) {
    __shared__ float w[HDIM * OUTDIM];  // 8 KiB
    for (int i = threadIdx.x; i < HDIM * OUTDIM; i += blockDim.x) w[i] = Wout[i];
    __syncthreads();
    int lane = threadIdx.x & 63;
    int half = lane >> 5;       // 2 nodes per wave
    int f = lane & 31;
    int wave = threadIdx.x >> 6;
    int node = (blockIdx.x * (blockDim.x >> 6) + wave) * 2 + half;
    if (node >= n) return;
    const float* hr = h + (size_t)node * HDIM;
    float acc = 0.f;
    #pragma unroll 8
    for (int k = 0; k < HDIM; k++) acc += hr[k] * w[k * OUTDIM + f];
    out[(size_t)node * OUTDIM + f] = acc;
}

extern "C" void kernel_launch(void* const* d_in, const int* in_sizes, int n_in,
                              void* d_out, int out_size, void* d_ws, size_t ws_size,
                              hipStream_t stream) {
    const float* x    = (const float*)d_in[0];
    const int*   ei   = (const int*)d_in[1];
    const float* Win  = (const float*)d_in[2];
    const float* Wl   = (const float*)d_in[3];
    const float* Wout = (const float*)d_in[4];
    float* out = (float*)d_out;

    int n = in_sizes[0] / INDIM;   // 100000
    int e = in_sizes[1] / 2;       // 1600000
    const int* dst = ei;           // edge_index[0]
    const int* src = ei + e;       // edge_index[1]

    // workspace layout
    char* w = (char*)d_ws;
    int* deg = (int*)w;      w += (size_t)n * 4;
    int* cursor = (int*)w;   w += (size_t)n * 4;     // contiguous with deg
    int* offs = (int*)w;     w += (size_t)(n + 1) * 4;
    w = (char*)(((uintptr_t)w + 255) & ~(uintptr_t)255);
    int* bsums = (int*)w;    w += 1024;
    int* csr_src = (int*)w;  w += (size_t)e * 4;
    float* csr_w = (float*)w; w += (size_t)e * 4;
    float* h = (float*)w;    w += (size_t)n * HDIM * 4;
    float* agg = (float*)w;  w += (size_t)n * HDIM * 4;

    // zero deg + cursor (contiguous)
    hipMemsetAsync(deg, 0, (size_t)2 * n * 4, stream);

    int tb = 256;
    // degrees
    deg_kernel<<<(e + tb - 1) / tb, tb, 0, stream>>>(dst, deg, e);
    // exclusive scan -> offs
    int nb = (n + SCAN_CHUNK - 1) / SCAN_CHUNK;     // 98
    scan_blocks<<<nb, 256, 0, stream>>>(deg, offs, bsums, n);
    scan_bsums<<<1, 64, 0, stream>>>(bsums, nb);
    scan_add<<<(n + tb - 1) / tb, tb, 0, stream>>>(offs, bsums, n, e);
    // CSR fill
    fill_csr<<<(e + tb - 1) / tb, tb, 0, stream>>>(dst, src, deg, offs, cursor,
                                                   csr_src, csr_w, e);
    // h = x @ W_in
    gemm_in<<<1024, 256, 0, stream>>>(x, Win, h, n);

    // two GCN layers
    for (int l = 0; l < 2; l++) {
        aggregate<<<(n + 3) / 4, 256, 0, stream>>>(h, offs, csr_src, csr_w, agg, n);
        gemm_layer<<<2048, 256, 0, stream>>>(agg, h, Wl + (size_t)l * HDIM * HDIM, n);
    }

    // out = h @ W_out
    gemm_out<<<(n + 7) / 8, 256, 0, stream>>>(h, Wout, out, n);
}

// Round 3
// 606.746 us; speedup vs baseline: 1.2922x; 1.2922x over previous
//
#include <hip/hip_runtime.h>
#include <hip/hip_bf16.h>

#define HDIM 64
#define INDIM 128
#define OUTDIM 32
#define SCAN_CHUNK 1024

// ---------------- degree count ----------------
__global__ void deg_kernel(const int* __restrict__ dst, int* __restrict__ deg, int e) {
    int i = blockIdx.x * blockDim.x + threadIdx.x;
    if (i < e) atomicAdd(&deg[dst[i]], 1);
}

// ---------------- 3-kernel exclusive scan of deg -> offs ----------------
__global__ void scan_blocks(const int* __restrict__ deg, int* __restrict__ offs,
                            int* __restrict__ bsums, int n) {
    __shared__ int sdata[256];
    int b = blockIdx.x, t = threadIdx.x;
    int base = b * SCAN_CHUNK + t * 4;
    int v[4];
    int s = 0;
    #pragma unroll
    for (int i = 0; i < 4; i++) {
        int idx = base + i;
        v[i] = (idx < n) ? deg[idx] : 0;
        s += v[i];
    }
    sdata[t] = s;
    __syncthreads();
    for (int off = 1; off < 256; off <<= 1) {
        int x = (t >= off) ? sdata[t - off] : 0;
        __syncthreads();
        sdata[t] += x;
        __syncthreads();
    }
    int run = sdata[t] - s;  // exclusive prefix of this thread within block
    #pragma unroll
    for (int i = 0; i < 4; i++) {
        int idx = base + i;
        if (idx < n) offs[idx] = run;
        run += v[i];
    }
    if (t == 255) bsums[b] = sdata[255];
}

__global__ void scan_bsums(int* __restrict__ bsums, int nb) {
    if (blockIdx.x == 0 && threadIdx.x == 0) {
        int run = 0;
        for (int b = 0; b < nb; b++) { int t = bsums[b]; bsums[b] = run; run += t; }
    }
}

__global__ void scan_add(int* __restrict__ offs, const int* __restrict__ bsums,
                         int n, int total) {
    int i = blockIdx.x * blockDim.x + threadIdx.x;
    if (i < n) offs[i] += bsums[i >> 10];
    if (i == 0) offs[n] = total;
}

// ---------------- CSR fill: entry = {src, bitcast(weight)} ----------------
__global__ void fill_csr(const int* __restrict__ dst, const int* __restrict__ src,
                         const int* __restrict__ deg, const int* __restrict__ offs,
                         int* __restrict__ cursor, int2* __restrict__ csr, int e) {
    int i = blockIdx.x * blockDim.x + threadIdx.x;
    if (i >= e) return;
    int d = dst[i], s = src[i];
    int pos = offs[d] + atomicAdd(&cursor[d], 1);
    float nd = (float)deg[d] + 1.0f;
    float ns = (float)deg[s] + 1.0f;
    csr[pos] = make_int2(s, __float_as_int(rsqrtf(nd * ns)));
}

// ---------------- h = x @ W_in  (128 -> 64) ----------------
__global__ void gemm_in(const float* __restrict__ x, const float* __restrict__ Win,
                        float* __restrict__ h, int n) {
    __shared__ float w[INDIM * HDIM];  // 32 KiB
    for (int i = threadIdx.x; i < INDIM * HDIM; i += blockDim.x) w[i] = Win[i];
    __syncthreads();
    int wave = threadIdx.x >> 6;
    int f = threadIdx.x & 63;
    int wpb = blockDim.x >> 6;
    for (int node = blockIdx.x * wpb + wave; node < n; node += gridDim.x * wpb) {
        const float* xr = x + (size_t)node * INDIM;
        float acc = 0.f;
        #pragma unroll 8
        for (int k = 0; k < INDIM; k++) acc += xr[k] * w[k * HDIM + f];
        h[(size_t)node * HDIM + f] = acc;
    }
}

// ---------------- agg[d] = sum_{e: dst=d} h[src]*w ----------------
// wave per node; 64-edge coalesced preload; 4x16-lane groups each own one
// edge (float4 row loads) -> 4 independent 256B loads in flight per trip.
// Trip count is wave-uniform (ceil(cnt/4)) with clamped shfl source lane so
// every ds_bpermute source is an ACTIVE lane (exec-mask hazard fix).
__global__ void aggregate(const float* __restrict__ h, const int* __restrict__ offs,
                          const int2* __restrict__ csr, float* __restrict__ agg, int n) {
    int wave = threadIdx.x >> 6;
    int lane = threadIdx.x & 63;
    int node = blockIdx.x * (blockDim.x >> 6) + wave;
    if (node >= n) return;
    int j0 = offs[node], j1 = offs[node + 1];
    int grp = lane >> 4;   // 0..3
    int gl = lane & 15;    // 0..15: float4 slot within row
    float4 acc = make_float4(0.f, 0.f, 0.f, 0.f);
    int j = j0;
    while (j < j1) {
        int cnt = min(j1 - j, 64);
        int2 ed = make_int2(0, 0);
        if (lane < cnt) ed = csr[j + lane];
        int trips = (cnt + 3) >> 2;
        for (int i = 0; i < trips; i++) {
            int t = 4 * i + grp;
            bool valid = (t < cnt);
            t = valid ? t : (cnt - 1);
            int s = __shfl(ed.x, t);
            float wt = __int_as_float(__shfl(ed.y, t));
            wt = valid ? wt : 0.f;
            float4 r = ((const float4*)(h + (size_t)s * HDIM))[gl];
            acc.x += wt * r.x;
            acc.y += wt * r.y;
            acc.z += wt * r.z;
            acc.w += wt * r.w;
        }
        j += cnt;
    }
    // reduce across the 4 groups (lane bits 4,5)
    #pragma unroll
    for (int m = 16; m < 64; m <<= 1) {
        acc.x += __shfl_xor(acc.x, m);
        acc.y += __shfl_xor(acc.y, m);
        acc.z += __shfl_xor(acc.z, m);
        acc.w += __shfl_xor(acc.w, m);
    }
    if (grp == 0)
        ((float4*)(agg + (size_t)node * HDIM))[gl] = acc;
}

// ---------------- h = relu((agg + h) @ W)  (64 -> 64, in-place) ----------------
__global__ void gemm_layer(const float* __restrict__ agg, float* __restrict__ h,
                           const float* __restrict__ W, int n) {
    __shared__ float w[HDIM * HDIM];  // 16 KiB
    for (int i = threadIdx.x; i < HDIM * HDIM; i += blockDim.x) w[i] = W[i];
    __syncthreads();
    int wave = threadIdx.x >> 6;
    int f = threadIdx.x & 63;
    int wpb = blockDim.x >> 6;
    for (int node = blockIdx.x * wpb + wave; node < n; node += gridDim.x * wpb) {
        float v = agg[(size_t)node * HDIM + f] + h[(size_t)node * HDIM + f];
        float acc = 0.f;
        #pragma unroll 8
        for (int k = 0; k < HDIM; k++) acc += __shfl(v, k) * w[k * HDIM + f];
        h[(size_t)node * HDIM + f] = fmaxf(acc, 0.f);
    }
}

// ---------------- out = h @ W_out  (64 -> 32) ----------------
__global__ void gemm_out(const float* __restrict__ h, const float* __restrict__ Wout,
                         float* __restrict__ out, int n) {
    __shared__ float w[HDIM * OUTDIM];  // 8 KiB
    for (int i = threadIdx.x; i < HDIM * OUTDIM; i += blockDim.x) w[i] = Wout[i];
    __syncthreads();
    int lane = threadIdx.x & 63;
    int half = lane >> 5;       // 2 nodes per wave
    int f = lane & 31;
    int wave = threadIdx.x >> 6;
    int node = (blockIdx.x * (blockDim.x >> 6) + wave) * 2 + half;
    if (node >= n) return;
    const float* hr = h + (size_t)node * HDIM;
    float acc = 0.f;
    #pragma unroll 8
    for (int k = 0; k < HDIM; k++) acc += hr[k] * w[k * OUTDIM + f];
    out[(size_t)node * OUTDIM + f] = acc;
}

extern "C" void kernel_launch(void* const* d_in, const int* in_sizes, int n_in,
                              void* d_out, int out_size, void* d_ws, size_t ws_size,
                              hipStream_t stream) {
    const float* x    = (const float*)d_in[0];
    const int*   ei   = (const int*)d_in[1];
    const float* Win  = (const float*)d_in[2];
    const float* Wl   = (const float*)d_in[3];
    const float* Wout = (const float*)d_in[4];
    float* out = (float*)d_out;

    int n = in_sizes[0] / INDIM;   // 100000
    int e = in_sizes[1] / 2;       // 1600000
    const int* dst = ei;           // edge_index[0]
    const int* src = ei + e;       // edge_index[1]

    // workspace layout
    char* w = (char*)d_ws;
    int* deg = (int*)w;      w += (size_t)n * 4;
    int* cursor = (int*)w;   w += (size_t)n * 4;     // contiguous with deg
    int* offs = (int*)w;     w += (size_t)(n + 1) * 4;
    w = (char*)(((uintptr_t)w + 255) & ~(uintptr_t)255);
    int* bsums = (int*)w;    w += 1024;
    int2* csr = (int2*)w;    w += (size_t)e * 8;
    float* h = (float*)w;    w += (size_t)n * HDIM * 4;
    float* agg = (float*)w;  w += (size_t)n * HDIM * 4;

    // zero deg + cursor (contiguous)
    hipMemsetAsync(deg, 0, (size_t)2 * n * 4, stream);

    int tb = 256;
    // degrees
    deg_kernel<<<(e + tb - 1) / tb, tb, 0, stream>>>(dst, deg, e);
    // exclusive scan -> offs
    int nb = (n + SCAN_CHUNK - 1) / SCAN_CHUNK;     // 98
    scan_blocks<<<nb, 256, 0, stream>>>(deg, offs, bsums, n);
    scan_bsums<<<1, 64, 0, stream>>>(bsums, nb);
    scan_add<<<(n + tb - 1) / tb, tb, 0, stream>>>(offs, bsums, n, e);
    // CSR fill
    fill_csr<<<(e + tb - 1) / tb, tb, 0, stream>>>(dst, src, deg, offs, cursor, csr, e);
    // h = x @ W_in
    gemm_in<<<1024, 256, 0, stream>>>(x, Win, h, n);

    // two GCN layers
    for (int l = 0; l < 2; l++) {
        aggregate<<<(n + 3) / 4, 256, 0, stream>>>(h, offs, csr, agg, n);
        gemm_layer<<<2048, 256, 0, stream>>>(agg, h, Wl + (size_t)l * HDIM * HDIM, n);
    }

    // out = h @ W_out
    gemm_out<<<(n + 7) / 8, 256, 0, stream>>>(h, Wout, out, n);
}

// Round 4
// 428.767 us; speedup vs baseline: 1.8286x; 1.4151x over previous
//
#include <hip/hip_runtime.h>
#include <hip/hip_bf16.h>

#define HDIM 64
#define INDIM 128
#define OUTDIM 32
#define SCAN_CHUNK 1024

// ---------------- degree count ----------------
__global__ void deg_kernel(const int* __restrict__ dst, int* __restrict__ deg, int e) {
    int i = blockIdx.x * blockDim.x + threadIdx.x;
    if (i < e) atomicAdd(&deg[dst[i]], 1);
}

// ---------------- 3-kernel exclusive scan of deg -> offs ----------------
__global__ void scan_blocks(const int* __restrict__ deg, int* __restrict__ offs,
                            int* __restrict__ bsums, int n) {
    __shared__ int sdata[256];
    int b = blockIdx.x, t = threadIdx.x;
    int base = b * SCAN_CHUNK + t * 4;
    int v[4];
    int s = 0;
    #pragma unroll
    for (int i = 0; i < 4; i++) {
        int idx = base + i;
        v[i] = (idx < n) ? deg[idx] : 0;
        s += v[i];
    }
    sdata[t] = s;
    __syncthreads();
    for (int off = 1; off < 256; off <<= 1) {
        int x = (t >= off) ? sdata[t - off] : 0;
        __syncthreads();
        sdata[t] += x;
        __syncthreads();
    }
    int run = sdata[t] - s;  // exclusive prefix of this thread within block
    #pragma unroll
    for (int i = 0; i < 4; i++) {
        int idx = base + i;
        if (idx < n) offs[idx] = run;
        run += v[i];
    }
    if (t == 255) bsums[b] = sdata[255];
}

__global__ void scan_bsums(int* __restrict__ bsums, int nb) {
    if (blockIdx.x == 0 && threadIdx.x == 0) {
        int run = 0;
        for (int b = 0; b < nb; b++) { int t = bsums[b]; bsums[b] = run; run += t; }
    }
}

__global__ void scan_add(int* __restrict__ offs, const int* __restrict__ bsums,
                         int n, int total) {
    int i = blockIdx.x * blockDim.x + threadIdx.x;
    if (i < n) offs[i] += bsums[i >> 10];
    if (i == 0) offs[n] = total;
}

// ---------------- CSR fill: entry = {src, bitcast(weight)} ----------------
__global__ void fill_csr(const int* __restrict__ dst, const int* __restrict__ src,
                         const int* __restrict__ deg, const int* __restrict__ offs,
                         int* __restrict__ cursor, int2* __restrict__ csr, int e) {
    int i = blockIdx.x * blockDim.x + threadIdx.x;
    if (i >= e) return;
    int d = dst[i], s = src[i];
    int pos = offs[d] + atomicAdd(&cursor[d], 1);
    float nd = (float)deg[d] + 1.0f;
    float ns = (float)deg[s] + 1.0f;
    csr[pos] = make_int2(s, __float_as_int(rsqrtf(nd * ns)));
}

// ---------------- register-blocked node GEMM: C = op(A [+Skip]) @ W ----------------
// A: n x K row-major, W: K x N row-major (staged in LDS), C: n x N.
// 256 threads, 128 nodes/block. Thread (tx,ty) computes R nodes x 8 feats.
// ADD_SKIP: A := A + Skip elementwise (fused); C may alias Skip (in-place:
// __syncthreads() separates last Skip read from first C write; blocks own
// disjoint row ranges). RELU: clamp at 0 in epilogue.
template<int K, int N, bool ADD_SKIP, bool RELU>
__global__ __launch_bounds__(256) void gemm_node(const float* __restrict__ A,
                                                 const float* __restrict__ Skip,
                                                 const float* __restrict__ W,
                                                 float* __restrict__ C, int n) {
    constexpr int TX = N / 8;        // col groups of 8 feats
    constexpr int TY = 256 / TX;     // row groups
    constexpr int BM = 128;          // nodes per block
    constexpr int R = BM / TY;       // nodes per thread
    __shared__ float w[K * N];
    for (int i = threadIdx.x; i < K * N; i += 256) w[i] = W[i];
    __syncthreads();
    int tx = (int)threadIdx.x % TX;
    int ty = (int)threadIdx.x / TX;
    int base = blockIdx.x * BM + ty * R;

    float acc[R][8];
    #pragma unroll
    for (int r = 0; r < R; r++)
        #pragma unroll
        for (int i = 0; i < 8; i++) acc[r][i] = 0.f;

    #pragma unroll 2
    for (int k = 0; k < K; k += 4) {
        float4 a4[R];
        #pragma unroll
        for (int r = 0; r < R; r++) {
            int node = base + r;
            if (node < n) {
                a4[r] = *(const float4*)(A + (size_t)node * K + k);
                if (ADD_SKIP) {
                    float4 s4 = *(const float4*)(Skip + (size_t)node * K + k);
                    a4[r].x += s4.x; a4[r].y += s4.y;
                    a4[r].z += s4.z; a4[r].w += s4.w;
                }
            } else {
                a4[r] = make_float4(0.f, 0.f, 0.f, 0.f);
            }
        }
        #pragma unroll
        for (int kk = 0; kk < 4; kk++) {
            float4 b0 = *(const float4*)(w + (k + kk) * N + tx * 8);
            float4 b1 = *(const float4*)(w + (k + kk) * N + tx * 8 + 4);
            #pragma unroll
            for (int r = 0; r < R; r++) {
                float av = (kk == 0) ? a4[r].x : (kk == 1) ? a4[r].y
                         : (kk == 2) ? a4[r].z : a4[r].w;
                acc[r][0] += av * b0.x; acc[r][1] += av * b0.y;
                acc[r][2] += av * b0.z; acc[r][3] += av * b0.w;
                acc[r][4] += av * b1.x; acc[r][5] += av * b1.y;
                acc[r][6] += av * b1.z; acc[r][7] += av * b1.w;
            }
        }
    }

    if (ADD_SKIP) __syncthreads();   // in-place safety: all Skip reads done

    #pragma unroll
    for (int r = 0; r < R; r++) {
        int node = base + r;
        if (node >= n) continue;
        float4 o0, o1;
        o0.x = RELU ? fmaxf(acc[r][0], 0.f) : acc[r][0];
        o0.y = RELU ? fmaxf(acc[r][1], 0.f) : acc[r][1];
        o0.z = RELU ? fmaxf(acc[r][2], 0.f) : acc[r][2];
        o0.w = RELU ? fmaxf(acc[r][3], 0.f) : acc[r][3];
        o1.x = RELU ? fmaxf(acc[r][4], 0.f) : acc[r][4];
        o1.y = RELU ? fmaxf(acc[r][5], 0.f) : acc[r][5];
        o1.z = RELU ? fmaxf(acc[r][6], 0.f) : acc[r][6];
        o1.w = RELU ? fmaxf(acc[r][7], 0.f) : acc[r][7];
        *(float4*)(C + (size_t)node * N + tx * 8) = o0;
        *(float4*)(C + (size_t)node * N + tx * 8 + 4) = o1;
    }
}

// ---------------- agg[d] = sum_{e: dst=d} h[src]*w ----------------
// wave per node; 64-edge coalesced preload; 4x16-lane groups each own one
// edge (float4 row loads) -> 4 independent 256B loads in flight per trip.
// Trip count is wave-uniform with clamped shfl source lane (exec-mask safe).
__global__ void aggregate(const float* __restrict__ h, const int* __restrict__ offs,
                          const int2* __restrict__ csr, float* __restrict__ agg, int n) {
    int wave = threadIdx.x >> 6;
    int lane = threadIdx.x & 63;
    int node = blockIdx.x * (blockDim.x >> 6) + wave;
    if (node >= n) return;
    int j0 = offs[node], j1 = offs[node + 1];
    int grp = lane >> 4;   // 0..3
    int gl = lane & 15;    // 0..15: float4 slot within row
    float4 acc = make_float4(0.f, 0.f, 0.f, 0.f);
    int j = j0;
    while (j < j1) {
        int cnt = min(j1 - j, 64);
        int2 ed = make_int2(0, 0);
        if (lane < cnt) ed = csr[j + lane];
        int trips = (cnt + 3) >> 2;
        for (int i = 0; i < trips; i++) {
            int t = 4 * i + grp;
            bool valid = (t < cnt);
            t = valid ? t : (cnt - 1);
            int s = __shfl(ed.x, t);
            float wt = __int_as_float(__shfl(ed.y, t));
            wt = valid ? wt : 0.f;
            float4 r = ((const float4*)(h + (size_t)s * HDIM))[gl];
            acc.x += wt * r.x;
            acc.y += wt * r.y;
            acc.z += wt * r.z;
            acc.w += wt * r.w;
        }
        j += cnt;
    }
    #pragma unroll
    for (int m = 16; m < 64; m <<= 1) {
        acc.x += __shfl_xor(acc.x, m);
        acc.y += __shfl_xor(acc.y, m);
        acc.z += __shfl_xor(acc.z, m);
        acc.w += __shfl_xor(acc.w, m);
    }
    if (grp == 0)
        ((float4*)(agg + (size_t)node * HDIM))[gl] = acc;
}

extern "C" void kernel_launch(void* const* d_in, const int* in_sizes, int n_in,
                              void* d_out, int out_size, void* d_ws, size_t ws_size,
                              hipStream_t stream) {
    const float* x    = (const float*)d_in[0];
    const int*   ei   = (const int*)d_in[1];
    const float* Win  = (const float*)d_in[2];
    const float* Wl   = (const float*)d_in[3];
    const float* Wout = (const float*)d_in[4];
    float* out = (float*)d_out;

    int n = in_sizes[0] / INDIM;   // 100000
    int e = in_sizes[1] / 2;       // 1600000
    const int* dst = ei;           // edge_index[0]
    const int* src = ei + e;       // edge_index[1]

    // workspace layout
    char* w = (char*)d_ws;
    int* deg = (int*)w;      w += (size_t)n * 4;
    int* cursor = (int*)w;   w += (size_t)n * 4;     // contiguous with deg
    int* offs = (int*)w;     w += (size_t)(n + 1) * 4;
    w = (char*)(((uintptr_t)w + 255) & ~(uintptr_t)255);
    int* bsums = (int*)w;    w += 1024;
    int2* csr = (int2*)w;    w += (size_t)e * 8;
    float* h = (float*)w;    w += (size_t)n * HDIM * 4;
    float* agg = (float*)w;  w += (size_t)n * HDIM * 4;

    // zero deg + cursor (contiguous)
    hipMemsetAsync(deg, 0, (size_t)2 * n * 4, stream);

    int tb = 256;
    // degrees
    deg_kernel<<<(e + tb - 1) / tb, tb, 0, stream>>>(dst, deg, e);
    // exclusive scan -> offs
    int nb = (n + SCAN_CHUNK - 1) / SCAN_CHUNK;     // 98
    scan_blocks<<<nb, 256, 0, stream>>>(deg, offs, bsums, n);
    scan_bsums<<<1, 64, 0, stream>>>(bsums, nb);
    scan_add<<<(n + tb - 1) / tb, tb, 0, stream>>>(offs, bsums, n, e);
    // CSR fill
    fill_csr<<<(e + tb - 1) / tb, tb, 0, stream>>>(dst, src, deg, offs, cursor, csr, e);

    int gblocks = (n + 127) / 128;
    // h = x @ W_in
    gemm_node<INDIM, HDIM, false, false><<<gblocks, 256, 0, stream>>>(x, nullptr, Win, h, n);

    // two GCN layers: agg = A_norm h; h = relu((agg + h) @ W_l)  (in-place)
    for (int l = 0; l < 2; l++) {
        aggregate<<<(n + 3) / 4, 256, 0, stream>>>(h, offs, csr, agg, n);
        gemm_node<HDIM, HDIM, true, true><<<gblocks, 256, 0, stream>>>(
            agg, h, Wl + (size_t)l * HDIM * HDIM, h, n);
    }

    // out = h @ W_out
    gemm_node<HDIM, OUTDIM, false, false><<<gblocks, 256, 0, stream>>>(h, nullptr, Wout, out, n);
}